// Round 1
// baseline (1424.658 us; speedup 1.0000x reference)
//
#include <hip/hip_runtime.h>
#include <math.h>

#define Hh 12
#define S_LEN 2048
#define D_MODEL 768
#define HD 64

static constexpr float MAXLS = 4.6051701859880914f; // log(1/0.01)

// ---------------- GEMM: C = A @ W^T + bias ----------------
// A: [M,K] row-major. W: [N,K] row-major (torch Linear weight).
// MODE 0: z in {0,1,2} selects (W,bias,dst); scatter dst to [B,H,S,DH].
// MODE 1: dst[m*N + n] plain row-major.
// Tile 128x128x16, 256 threads, 8x8 micro-tile per thread.
template<int MODE>
__global__ __launch_bounds__(256)
void gemm_tn(const float* __restrict__ A,
             const float* __restrict__ Wa, const float* __restrict__ Wb, const float* __restrict__ Wc,
             const float* __restrict__ ba, const float* __restrict__ bb, const float* __restrict__ bc,
             float* __restrict__ Da, float* __restrict__ Db, float* __restrict__ Dc,
             int M, int N, int K)
{
    const float* W; const float* bias; float* D;
    if (MODE == 0) {
        const int z = blockIdx.z;
        W    = (z == 0) ? Wa : (z == 1) ? Wb : Wc;
        bias = (z == 0) ? ba : (z == 1) ? bb : bc;
        D    = (z == 0) ? Da : (z == 1) ? Db : Dc;
    } else {
        W = Wa; bias = ba; D = Da;
    }

    // [K][M] layout so compute reads are contiguous b128; +4 pad spreads store banks
    __shared__ float As[16][132];
    __shared__ float Bs[16][132];

    const int tid = threadIdx.x;
    const int tx  = tid & 15;      // micro-tile col group
    const int ty  = tid >> 4;      // micro-tile row group
    const int m0  = blockIdx.y * 128;
    const int n0  = blockIdx.x * 128;
    const int lr  = tid >> 2;      // 0..63 load row
    const int lc  = tid & 3;       // 0..3  load col group (x4 floats)

    float acc[8][8];
    #pragma unroll
    for (int i = 0; i < 8; ++i)
        #pragma unroll
        for (int j = 0; j < 8; ++j) acc[i][j] = 0.0f;

    const float* Ar0 = A + (size_t)(m0 + lr) * K + lc * 4;
    const float* Ar1 = Ar0 + (size_t)64 * K;
    const float* Wr0 = W + (size_t)(n0 + lr) * K + lc * 4;
    const float* Wr1 = Wr0 + (size_t)64 * K;

    for (int k0 = 0; k0 < K; k0 += 16) {
        const float4 a0 = *(const float4*)(Ar0 + k0);
        const float4 a1 = *(const float4*)(Ar1 + k0);
        const float4 w0 = *(const float4*)(Wr0 + k0);
        const float4 w1 = *(const float4*)(Wr1 + k0);
        __syncthreads();   // previous iteration's compute reads done
        {
            const int kb = lc * 4;
            As[kb+0][lr]    = a0.x; As[kb+1][lr]    = a0.y; As[kb+2][lr]    = a0.z; As[kb+3][lr]    = a0.w;
            As[kb+0][lr+64] = a1.x; As[kb+1][lr+64] = a1.y; As[kb+2][lr+64] = a1.z; As[kb+3][lr+64] = a1.w;
            Bs[kb+0][lr]    = w0.x; Bs[kb+1][lr]    = w0.y; Bs[kb+2][lr]    = w0.z; Bs[kb+3][lr]    = w0.w;
            Bs[kb+0][lr+64] = w1.x; Bs[kb+1][lr+64] = w1.y; Bs[kb+2][lr+64] = w1.z; Bs[kb+3][lr+64] = w1.w;
        }
        __syncthreads();
        #pragma unroll
        for (int k = 0; k < 16; ++k) {
            const float4 af0 = *(const float4*)&As[k][ty*8];
            const float4 af1 = *(const float4*)&As[k][ty*8+4];
            const float4 bf0 = *(const float4*)&Bs[k][tx*8];
            const float4 bf1 = *(const float4*)&Bs[k][tx*8+4];
            const float am[8] = {af0.x,af0.y,af0.z,af0.w,af1.x,af1.y,af1.z,af1.w};
            const float bm[8] = {bf0.x,bf0.y,bf0.z,bf0.w,bf1.x,bf1.y,bf1.z,bf1.w};
            #pragma unroll
            for (int i = 0; i < 8; ++i)
                #pragma unroll
                for (int j = 0; j < 8; ++j)
                    acc[i][j] = __builtin_fmaf(am[i], bm[j], acc[i][j]);
        }
    }

    // epilogue
    #pragma unroll
    for (int i = 0; i < 8; ++i) {
        const int m = m0 + ty * 8 + i;
        #pragma unroll
        for (int jg = 0; jg < 2; ++jg) {
            const int n = n0 + tx * 8 + jg * 4;
            float4 r;
            r.x = acc[i][jg*4+0] + bias[n+0];
            r.y = acc[i][jg*4+1] + bias[n+1];
            r.z = acc[i][jg*4+2] + bias[n+2];
            r.w = acc[i][jg*4+3] + bias[n+3];
            if (MODE == 0) {
                const int b = m >> 11;        // /S_LEN
                const int s = m & (S_LEN-1);
                const int h = n >> 6;
                const int d = n & 63;
                *(float4*)&D[(((size_t)b*Hh + h)*S_LEN + s)*HD + d] = r;
            } else {
                *(float4*)&D[(size_t)m * N + n] = r;
            }
        }
    }
}

// ---------------- L2 normalize q,k rows; fold per-head scale into q ----------------
__global__ __launch_bounds__(256)
void norm_qk(float* __restrict__ qb, float* __restrict__ kb,
             const float* __restrict__ logit_scale, int rowsPerBuf)
{
    const int row  = blockIdx.x * 4 + (threadIdx.x >> 6);
    const int lane = threadIdx.x & 63;
    const bool isQ = (row < rowsPerBuf);
    const int r = isQ ? row : (row - rowsPerBuf);
    float* p = (isQ ? qb : kb) + (size_t)r * HD;
    const float x = p[lane];
    float ss = x * x;
    #pragma unroll
    for (int m = 1; m < 64; m <<= 1) ss += __shfl_xor(ss, m, 64);
    const float nrm = sqrtf(ss);
    float inv = 1.0f / fmaxf(nrm, 1e-12f);
    if (isQ) {
        const int h = (r / S_LEN) % Hh;
        inv *= expf(fminf(logit_scale[h], MAXLS));
    }
    p[lane] = x * inv;
}

// ---------------- Flash attention, fp32, 64x64 tiles ----------------
// grid: (S/64, B*H), block 256. q is pre-normalized AND pre-scaled; k pre-normalized.
__global__ __launch_bounds__(256)
void attn(const float* __restrict__ q, const float* __restrict__ k,
          const float* __restrict__ v, float* __restrict__ ctx)
{
    __shared__ float smem[16384];     // 64 KiB total
    float* Qs = smem;                 // [d][r] 64x64
    float* Ks = smem + 4096;          // [d][c] 64x64
    float* Vs = smem + 8192;          // [kk][d] 64x64
    float* Ps = smem + 12288;         // [c][r] 64x64

    const int bh = blockIdx.y;
    const int q0 = blockIdx.x * 64;
    const float* qb = q + (size_t)bh * S_LEN * HD;
    const float* kb = k + (size_t)bh * S_LEN * HD;
    const float* vb = v + (size_t)bh * S_LEN * HD;

    const int tid = threadIdx.x;
    const int tx = tid & 15, ty = tid >> 4;
    const int lr = tid >> 2, lc = tid & 3;

    // Q tile -> LDS transposed [d][r]
    {
        const float* src = qb + (size_t)(q0 + lr) * HD;
        #pragma unroll
        for (int qq = 0; qq < 4; ++qq) {
            const float4 f = *(const float4*)(src + (4*qq + lc) * 4);
            const int d0 = (4*qq + lc) * 4;
            Qs[(d0+0)*64 + lr] = f.x;
            Qs[(d0+1)*64 + lr] = f.y;
            Qs[(d0+2)*64 + lr] = f.z;
            Qs[(d0+3)*64 + lr] = f.w;
        }
    }

    float acc[4][4];
    float mrun[4], lrun[4];
    #pragma unroll
    for (int i = 0; i < 4; ++i) {
        mrun[i] = -INFINITY; lrun[i] = 0.0f;
        #pragma unroll
        for (int j = 0; j < 4; ++j) acc[i][j] = 0.0f;
    }
    __syncthreads();

    for (int kt = 0; kt < S_LEN/64; ++kt) {
        const float* ksrc = kb + (size_t)(kt*64 + lr) * HD;
        const float* vsrc = vb + (size_t)(kt*64 + lr) * HD;
        float4 kf[4], vf[4];
        #pragma unroll
        for (int qq = 0; qq < 4; ++qq) {
            kf[qq] = *(const float4*)(ksrc + (4*qq + lc) * 4);
            vf[qq] = *(const float4*)(vsrc + (4*qq + lc) * 4);
        }
        __syncthreads();   // previous iteration's PV reads done
        #pragma unroll
        for (int qq = 0; qq < 4; ++qq) {
            const int d0 = (4*qq + lc) * 4;
            Ks[(d0+0)*64 + lr] = kf[qq].x;
            Ks[(d0+1)*64 + lr] = kf[qq].y;
            Ks[(d0+2)*64 + lr] = kf[qq].z;
            Ks[(d0+3)*64 + lr] = kf[qq].w;
            *(float4*)&Vs[lr*64 + d0] = vf[qq];
        }
        __syncthreads();

        // S = Q @ K^T  (q pre-scaled)
        float sv[4][4];
        #pragma unroll
        for (int i = 0; i < 4; ++i)
            #pragma unroll
            for (int j = 0; j < 4; ++j) sv[i][j] = 0.0f;
        #pragma unroll 8
        for (int d = 0; d < 64; ++d) {
            const float4 qf = *(const float4*)&Qs[d*64 + ty*4];
            const float4 kr = *(const float4*)&Ks[d*64 + tx*4];
            const float qa[4] = {qf.x,qf.y,qf.z,qf.w};
            const float ka[4] = {kr.x,kr.y,kr.z,kr.w};
            #pragma unroll
            for (int i = 0; i < 4; ++i)
                #pragma unroll
                for (int j = 0; j < 4; ++j)
                    sv[i][j] = __builtin_fmaf(qa[i], ka[j], sv[i][j]);
        }

        // online softmax (rows ty*4..+3, reduce across 16 tx lanes)
        float p[4][4];
        #pragma unroll
        for (int i = 0; i < 4; ++i) {
            float rm = fmaxf(fmaxf(sv[i][0], sv[i][1]), fmaxf(sv[i][2], sv[i][3]));
            #pragma unroll
            for (int mm = 1; mm < 16; mm <<= 1) rm = fmaxf(rm, __shfl_xor(rm, mm, 64));
            const float mn = fmaxf(mrun[i], rm);
            const float fct = __expf(mrun[i] - mn);
            mrun[i] = mn;
            float rs = 0.0f;
            #pragma unroll
            for (int j = 0; j < 4; ++j) { p[i][j] = __expf(sv[i][j] - mn); rs += p[i][j]; }
            #pragma unroll
            for (int mm = 1; mm < 16; mm <<= 1) rs += __shfl_xor(rs, mm, 64);
            lrun[i] = lrun[i] * fct + rs;
            #pragma unroll
            for (int j = 0; j < 4; ++j) acc[i][j] *= fct;
        }

        // P^T -> LDS [c][r]
        #pragma unroll
        for (int j = 0; j < 4; ++j) {
            const float4 col = {p[0][j], p[1][j], p[2][j], p[3][j]};
            *(float4*)&Ps[(tx*4 + j)*64 + ty*4] = col;
        }
        __syncthreads();

        // acc += P @ V
        #pragma unroll 8
        for (int kk = 0; kk < 64; ++kk) {
            const float4 pf = *(const float4*)&Ps[kk*64 + ty*4];
            const float4 vr = *(const float4*)&Vs[kk*64 + tx*4];
            const float pa[4] = {pf.x,pf.y,pf.z,pf.w};
            const float va[4] = {vr.x,vr.y,vr.z,vr.w};
            #pragma unroll
            for (int i = 0; i < 4; ++i)
                #pragma unroll
                for (int j = 0; j < 4; ++j)
                    acc[i][j] = __builtin_fmaf(pa[i], va[j], acc[i][j]);
        }
    }

    // write ctx in [B,S,D] layout (ready for output projection)
    const int b = bh / Hh, h = bh % Hh;
    #pragma unroll
    for (int i = 0; i < 4; ++i) {
        const float inv = 1.0f / lrun[i];
        const int s = q0 + ty*4 + i;
        const float4 r = {acc[i][0]*inv, acc[i][1]*inv, acc[i][2]*inv, acc[i][3]*inv};
        *(float4*)&ctx[((size_t)b*S_LEN + s)*D_MODEL + h*HD + tx*4] = r;
    }
}

extern "C" void kernel_launch(void* const* d_in, const int* in_sizes, int n_in,
                              void* d_out, int out_size, void* d_ws, size_t ws_size,
                              hipStream_t stream)
{
    const float* hs = (const float*)d_in[0];
    const float* Wq = (const float*)d_in[1];
    const float* bq = (const float*)d_in[2];
    const float* Wk = (const float*)d_in[3];
    const float* bk = (const float*)d_in[4];
    const float* Wv = (const float*)d_in[5];
    const float* bv = (const float*)d_in[6];
    const float* Wo = (const float*)d_in[7];
    const float* bo = (const float*)d_in[8];
    const float* ls = (const float*)d_in[9];
    float* out = (float*)d_out;

    const int B = 4;
    const int M = B * S_LEN;                    // 8192
    const size_t perBuf = (size_t)B * Hh * S_LEN * HD;  // 6291456 floats

    float* qbuf = (float*)d_ws;
    float* kbuf = qbuf + perBuf;
    float* vbuf = kbuf + perBuf;
    float* cbuf = vbuf + perBuf;                // needs ~101 MB of d_ws total

    // QKV projections, scatter to [B,H,S,DH]
    dim3 g1(D_MODEL/128, M/128, 3);
    hipLaunchKernelGGL((gemm_tn<0>), g1, dim3(256), 0, stream,
                       hs, Wq, Wk, Wv, bq, bk, bv, qbuf, kbuf, vbuf, M, D_MODEL, D_MODEL);

    // L2-normalize q,k; fold exp(min(logit_scale, log 100)) into q
    const int rows = B * Hh * S_LEN;
    hipLaunchKernelGGL(norm_qk, dim3(2*rows/4), dim3(256), 0, stream, qbuf, kbuf, ls, rows);

    // flash attention -> ctx [B,S,D]
    hipLaunchKernelGGL(attn, dim3(S_LEN/64, B*Hh), dim3(256), 0, stream, qbuf, kbuf, vbuf, cbuf);

    // output projection -> d_out
    dim3 g2(D_MODEL/128, M/128, 1);
    hipLaunchKernelGGL((gemm_tn<1>), g2, dim3(256), 0, stream,
                       cbuf, Wo, nullptr, nullptr, bo, nullptr, nullptr,
                       out, nullptr, nullptr, M, D_MODEL, D_MODEL);
}

// Round 2
// 786.657 us; speedup vs baseline: 1.8110x; 1.8110x over previous
//
#include <hip/hip_runtime.h>
#include <math.h>

#define Hh 12
#define S_LEN 2048
#define D_MODEL 768
#define HD 64

static constexpr float MAXLS = 4.6051701859880914f; // log(1/0.01)

typedef short bf16x8 __attribute__((ext_vector_type(8)));
typedef float f32x4  __attribute__((ext_vector_type(4)));
typedef unsigned short u16x8 __attribute__((ext_vector_type(8)));

__device__ __forceinline__ unsigned short f2bf(float x) {
    unsigned int u = __builtin_bit_cast(unsigned int, x);
    unsigned int r = (u + 0x7FFF + ((u >> 16) & 1)) >> 16;
    return (unsigned short)r;
}

// ---------------- GEMM: C = A @ W^T + bias ----------------
// MODE 0: z in {0,1,2}; z<2: fp32 scatter to [B,H,S,DH]; z==2: bf16 V^T to [B,H,DH,S].
// MODE 1: fp32 row-major [M,N].
template<int MODE>
__global__ __launch_bounds__(256)
void gemm_tn(const float* __restrict__ A,
             const float* __restrict__ Wa, const float* __restrict__ Wb, const float* __restrict__ Wc,
             const float* __restrict__ ba, const float* __restrict__ bb, const float* __restrict__ bc,
             float* __restrict__ Da, float* __restrict__ Db, float* __restrict__ Dc,
             int M, int N, int K)
{
    const float* W; const float* bias; float* D; int z = 0;
    if (MODE == 0) {
        z = blockIdx.z;
        W    = (z == 0) ? Wa : (z == 1) ? Wb : Wc;
        bias = (z == 0) ? ba : (z == 1) ? bb : bc;
        D    = (z == 0) ? Da : (z == 1) ? Db : Dc;
    } else {
        W = Wa; bias = ba; D = Da;
    }

    __shared__ float As[16][132];
    __shared__ float Bs[16][132];

    const int tid = threadIdx.x;
    const int tx  = tid & 15;
    const int ty  = tid >> 4;
    const int m0  = blockIdx.y * 128;
    const int n0  = blockIdx.x * 128;
    const int lr  = tid >> 2;
    const int lc  = tid & 3;

    float acc[8][8];
    #pragma unroll
    for (int i = 0; i < 8; ++i)
        #pragma unroll
        for (int j = 0; j < 8; ++j) acc[i][j] = 0.0f;

    const float* Ar0 = A + (size_t)(m0 + lr) * K + lc * 4;
    const float* Ar1 = Ar0 + (size_t)64 * K;
    const float* Wr0 = W + (size_t)(n0 + lr) * K + lc * 4;
    const float* Wr1 = Wr0 + (size_t)64 * K;

    for (int k0 = 0; k0 < K; k0 += 16) {
        const float4 a0 = *(const float4*)(Ar0 + k0);
        const float4 a1 = *(const float4*)(Ar1 + k0);
        const float4 w0 = *(const float4*)(Wr0 + k0);
        const float4 w1 = *(const float4*)(Wr1 + k0);
        __syncthreads();
        {
            const int kb = lc * 4;
            As[kb+0][lr]    = a0.x; As[kb+1][lr]    = a0.y; As[kb+2][lr]    = a0.z; As[kb+3][lr]    = a0.w;
            As[kb+0][lr+64] = a1.x; As[kb+1][lr+64] = a1.y; As[kb+2][lr+64] = a1.z; As[kb+3][lr+64] = a1.w;
            Bs[kb+0][lr]    = w0.x; Bs[kb+1][lr]    = w0.y; Bs[kb+2][lr]    = w0.z; Bs[kb+3][lr]    = w0.w;
            Bs[kb+0][lr+64] = w1.x; Bs[kb+1][lr+64] = w1.y; Bs[kb+2][lr+64] = w1.z; Bs[kb+3][lr+64] = w1.w;
        }
        __syncthreads();
        #pragma unroll
        for (int k = 0; k < 16; ++k) {
            const float4 af0 = *(const float4*)&As[k][ty*8];
            const float4 af1 = *(const float4*)&As[k][ty*8+4];
            const float4 bf0 = *(const float4*)&Bs[k][tx*8];
            const float4 bf1 = *(const float4*)&Bs[k][tx*8+4];
            const float am[8] = {af0.x,af0.y,af0.z,af0.w,af1.x,af1.y,af1.z,af1.w};
            const float bm[8] = {bf0.x,bf0.y,bf0.z,bf0.w,bf1.x,bf1.y,bf1.z,bf1.w};
            #pragma unroll
            for (int i = 0; i < 8; ++i)
                #pragma unroll
                for (int j = 0; j < 8; ++j)
                    acc[i][j] = __builtin_fmaf(am[i], bm[j], acc[i][j]);
        }
    }

    if (MODE == 0 && z == 2) {
        // V^T bf16: vT[((b*Hh+h)*HD + d)*S_LEN + s]
        const int b = m0 >> 11;
        const int s0 = (m0 & (S_LEN-1)) + ty * 8;
        unsigned short* VT = (unsigned short*)D;
        #pragma unroll
        for (int j = 0; j < 8; ++j) {
            const int n = n0 + tx*8 + j;
            const int h = n >> 6, d = n & 63;
            const float bn = bias[n];
            u16x8 o;
            #pragma unroll
            for (int i = 0; i < 8; ++i) o[i] = f2bf(acc[i][j] + bn);
            *(u16x8*)(VT + (((size_t)b*Hh + h)*HD + d)*S_LEN + s0) = o;
        }
        return;
    }

    #pragma unroll
    for (int i = 0; i < 8; ++i) {
        const int m = m0 + ty * 8 + i;
        #pragma unroll
        for (int jg = 0; jg < 2; ++jg) {
            const int n = n0 + tx * 8 + jg * 4;
            float4 r;
            r.x = acc[i][jg*4+0] + bias[n+0];
            r.y = acc[i][jg*4+1] + bias[n+1];
            r.z = acc[i][jg*4+2] + bias[n+2];
            r.w = acc[i][jg*4+3] + bias[n+3];
            if (MODE == 0) {
                const int b = m >> 11;
                const int s = m & (S_LEN-1);
                const int h = n >> 6;
                const int d = n & 63;
                *(float4*)&D[(((size_t)b*Hh + h)*S_LEN + s)*HD + d] = r;
            } else {
                *(float4*)&D[(size_t)m * N + n] = r;
            }
        }
    }
}

// ---------------- L2 normalize q,k rows; fold per-head scale into q; write bf16 in-place ----------------
// Row r (fp32, 256B): bf16 result written to first 128B of the same row. Safe within-wave.
__global__ __launch_bounds__(256)
void norm_qk(float* __restrict__ qb, float* __restrict__ kb,
             const float* __restrict__ logit_scale, int rowsPerBuf)
{
    const int row  = blockIdx.x * 4 + (threadIdx.x >> 6);
    const int lane = threadIdx.x & 63;
    const bool isQ = (row < rowsPerBuf);
    const int r = isQ ? row : (row - rowsPerBuf);
    float* p = (isQ ? qb : kb) + (size_t)r * HD;
    const float x = p[lane];
    float ss = x * x;
    #pragma unroll
    for (int m = 1; m < 64; m <<= 1) ss += __shfl_xor(ss, m, 64);
    const float nrm = sqrtf(ss);
    float inv = 1.0f / fmaxf(nrm, 1e-12f);
    if (isQ) {
        const int h = (r / S_LEN) % Hh;
        inv *= expf(fminf(logit_scale[h], MAXLS));
    }
    ((unsigned short*)p)[lane] = f2bf(x * inv);
}

// ---------------- stage a 64x64 bf16 tile into LDS with XOR chunk swizzle ----------------
// global row stride = grs bytes; LDS rows are 128B; phys chunk = (kc ^ (row&7)).
__device__ __forceinline__ void stage_tile(const char* __restrict__ g, int grs,
                                           char* __restrict__ lds, int tid)
{
    #pragma unroll
    for (int i = 0; i < 2; ++i) {
        const int c = tid * 2 + i;            // 0..511
        const int row = c >> 3, kc = c & 7;
        const uint4 v = *(const uint4*)(g + (size_t)row * grs + kc * 16);
        *(uint4*)(lds + row * 128 + ((kc ^ (row & 7)) << 4)) = v;
    }
}

// ---------------- Flash attention, bf16 MFMA, 64x64 tiles, 4 waves ----------------
// q,k: bf16 rows (128B payload, 256B stride). vT: bf16 [B,H,DH,S] (4096B row stride).
__global__ __launch_bounds__(256)
void attn_mfma(const char* __restrict__ qb_, const char* __restrict__ kb_,
               const char* __restrict__ vtb_, float* __restrict__ ctx)
{
    __shared__ char smem[32768];
    char* Qs = smem;            // [64 q][64 k] bf16 swz
    char* Ks = smem + 8192;     // [64 kv][64 k] bf16 swz
    char* Vs = smem + 16384;    // [64 d][64 kv] bf16 swz (from vT)
    char* Ps = smem + 24576;    // [64 q][64 kv] bf16 swz

    // XCD-aware decode: each XCD owns 6 complete (b,h) pairs
    const int flat = blockIdx.x;              // 0..1535
    const int xcd  = flat & 7;
    const int ix   = flat >> 3;               // 0..191
    const int bh   = xcd * 6 + (ix >> 5);
    const int q0   = (ix & 31) * 64;

    const int tid = threadIdx.x;
    const int l   = tid & 63;
    const int w   = tid >> 6;
    const int lg  = l >> 4;                   // 16-lane group 0..3
    const int ll  = l & 15;

    const char* qg = qb_ + ((size_t)bh * S_LEN + q0) * 256;
    const char* kg = kb_ + (size_t)bh * S_LEN * 256;
    const char* vg = vtb_ + (size_t)bh * HD * (S_LEN * 2);

    stage_tile(qg, 256, Qs, tid);

    const int m = w * 16 + ll;                // this lane's A-frag row (q row in tile)
    f32x4 acco[4];
    float mrun[4], lrun[4];
    #pragma unroll
    for (int i = 0; i < 4; ++i) {
        mrun[i] = -INFINITY; lrun[i] = 0.0f;
        acco[i] = (f32x4){0.f, 0.f, 0.f, 0.f};
    }
    __syncthreads();

    bf16x8 aq[2];
    #pragma unroll
    for (int kk = 0; kk < 2; ++kk) {
        const int k8 = kk * 4 + lg;
        aq[kk] = *(const bf16x8*)(Qs + m * 128 + ((k8 ^ (m & 7)) << 4));
    }

    for (int kt = 0; kt < S_LEN / 64; ++kt) {
        __syncthreads();   // prev PV reads (Vs/Ps) done before restage
        stage_tile(kg + (size_t)kt * 64 * 256, 256, Ks, tid);
        stage_tile(vg + kt * 128, S_LEN * 2, Vs, tid);
        __syncthreads();

        // S-tile = Q K^T : 4 col-tiles x K=64
        f32x4 accs[4];
        #pragma unroll
        for (int t = 0; t < 4; ++t) accs[t] = (f32x4){0.f, 0.f, 0.f, 0.f};
        #pragma unroll
        for (int kk = 0; kk < 2; ++kk) {
            const int k8 = kk * 4 + lg;
            #pragma unroll
            for (int t = 0; t < 4; ++t) {
                const int n = t * 16 + ll;
                const bf16x8 bk = *(const bf16x8*)(Ks + n * 128 + ((k8 ^ (n & 7)) << 4));
                accs[t] = __builtin_amdgcn_mfma_f32_16x16x32_bf16(aq[kk], bk, accs[t], 0, 0, 0);
            }
        }

        // online softmax: lane covers rows w*16 + lg*4 + i, cols t*16 + ll
        float p[4][4]; float fct[4];
        #pragma unroll
        for (int i = 0; i < 4; ++i) {
            float rm = fmaxf(fmaxf(accs[0][i], accs[1][i]), fmaxf(accs[2][i], accs[3][i]));
            #pragma unroll
            for (int mm = 1; mm < 16; mm <<= 1) rm = fmaxf(rm, __shfl_xor(rm, mm, 64));
            const float mn = fmaxf(mrun[i], rm);
            fct[i] = __expf(mrun[i] - mn);
            mrun[i] = mn;
            float rs = 0.0f;
            #pragma unroll
            for (int t = 0; t < 4; ++t) { p[t][i] = __expf(accs[t][i] - mn); rs += p[t][i]; }
            #pragma unroll
            for (int mm = 1; mm < 16; mm <<= 1) rs += __shfl_xor(rs, mm, 64);
            lrun[i] = lrun[i] * fct[i] + rs;
        }
        #pragma unroll
        for (int t = 0; t < 4; ++t)
            #pragma unroll
            for (int i = 0; i < 4; ++i) acco[t][i] *= fct[i];

        // P -> LDS (bf16, swizzled). Row mi = w*16 + lg*4 + i, col = t*16 + ll.
        #pragma unroll
        for (int t = 0; t < 4; ++t) {
            #pragma unroll
            for (int i = 0; i < 4; ++i) {
                const int mi  = w * 16 + lg * 4 + i;
                const int col = t * 16 + ll;
                const int off = mi * 128 + (((col >> 3) ^ (mi & 7)) << 4) + (col & 7) * 2;
                *(unsigned short*)(Ps + off) = f2bf(p[t][i]);
            }
        }
        __syncthreads();

        // O += P V : A from Ps (wave-local rows), B from Vs
        #pragma unroll
        for (int kk = 0; kk < 2; ++kk) {
            const int k8 = kk * 4 + lg;
            const bf16x8 pa = *(const bf16x8*)(Ps + m * 128 + ((k8 ^ (m & 7)) << 4));
            #pragma unroll
            for (int t = 0; t < 4; ++t) {
                const int dn = t * 16 + ll;
                const bf16x8 bv = *(const bf16x8*)(Vs + dn * 128 + ((k8 ^ (dn & 7)) << 4));
                acco[t] = __builtin_amdgcn_mfma_f32_16x16x32_bf16(pa, bv, acco[t], 0, 0, 0);
            }
        }
    }

    // epilogue: ctx[b][s][h*64+d] fp32
    const int b = bh / Hh, h = bh % Hh;
    #pragma unroll
    for (int i = 0; i < 4; ++i) {
        const float inv = 1.0f / lrun[i];
        const int s = q0 + w * 16 + lg * 4 + i;
        float* crow = ctx + ((size_t)b * S_LEN + s) * D_MODEL + h * HD;
        #pragma unroll
        for (int t = 0; t < 4; ++t) crow[t * 16 + ll] = acco[t][i] * inv;
    }
}

extern "C" void kernel_launch(void* const* d_in, const int* in_sizes, int n_in,
                              void* d_out, int out_size, void* d_ws, size_t ws_size,
                              hipStream_t stream)
{
    const float* hs = (const float*)d_in[0];
    const float* Wq = (const float*)d_in[1];
    const float* bq = (const float*)d_in[2];
    const float* Wk = (const float*)d_in[3];
    const float* bk = (const float*)d_in[4];
    const float* Wv = (const float*)d_in[5];
    const float* bv = (const float*)d_in[6];
    const float* Wo = (const float*)d_in[7];
    const float* bo = (const float*)d_in[8];
    const float* ls = (const float*)d_in[9];
    float* out = (float*)d_out;

    const int B = 4;
    const int M = B * S_LEN;                              // 8192
    const size_t perBuf = (size_t)B * Hh * S_LEN * HD;    // 6291456

    float* qbuf = (float*)d_ws;                 // fp32 -> bf16 in-place (256B rows)
    float* kbuf = qbuf + perBuf;
    float* vtb  = kbuf + perBuf;                // bf16 V^T [B,H,DH,S] (perBuf/2 floats)
    float* cbuf = vtb + perBuf / 2;             // fp32 ctx [B,S,D]

    // QKV projections: q,k fp32 scatter; v -> bf16 transposed
    dim3 g1(D_MODEL/128, M/128, 3);
    hipLaunchKernelGGL((gemm_tn<0>), g1, dim3(256), 0, stream,
                       hs, Wq, Wk, Wv, bq, bk, bv, qbuf, kbuf, vtb, M, D_MODEL, D_MODEL);

    // normalize q,k; fold exp(min(ls,log100)) into q; emit bf16 in-place
    const int rows = B * Hh * S_LEN;
    hipLaunchKernelGGL(norm_qk, dim3(2*rows/4), dim3(256), 0, stream, qbuf, kbuf, ls, rows);

    // flash attention (bf16 MFMA) -> ctx fp32 [B,S,D]
    hipLaunchKernelGGL(attn_mfma, dim3(32 * B * Hh), dim3(256), 0, stream,
                       (const char*)qbuf, (const char*)kbuf, (const char*)vtb, cbuf);

    // output projection -> d_out
    dim3 g2(D_MODEL/128, M/128, 1);
    hipLaunchKernelGGL((gemm_tn<1>), g2, dim3(256), 0, stream,
                       cbuf, Wo, nullptr, nullptr, bo, nullptr, nullptr,
                       out, nullptr, nullptr, M, D_MODEL, D_MODEL);
}

// Round 3
// 332.723 us; speedup vs baseline: 4.2818x; 2.3643x over previous
//
#include <hip/hip_runtime.h>
#include <math.h>

#define Hh 12
#define S_LEN 2048
#define D_MODEL 768
#define HD 64

static constexpr float MAXLS = 4.6051701859880914f; // log(1/0.01)

typedef short bf16x8 __attribute__((ext_vector_type(8)));
typedef float f32x4  __attribute__((ext_vector_type(4)));
typedef unsigned short u16x4 __attribute__((ext_vector_type(4)));
typedef unsigned short u16x8 __attribute__((ext_vector_type(8)));

__device__ __forceinline__ unsigned short f2bf(float x) {
    unsigned int u = __builtin_bit_cast(unsigned int, x);
    unsigned int r = (u + 0x7FFF + ((u >> 16) & 1)) >> 16;
    return (unsigned short)r;
}

__device__ __forceinline__ void gload16(const void* g, void* l) {
    __builtin_amdgcn_global_load_lds(
        (const __attribute__((address_space(1))) unsigned int*)g,
        (__attribute__((address_space(3))) unsigned int*)l, 16, 0, 0);
}

// ---------------- fp32 -> bf16 convert: hs, Wq|Wk|Wv (concat), Wo ----------------
__global__ __launch_bounds__(256)
void convert_bf16(const float* __restrict__ hs,
                  const float* __restrict__ Wq, const float* __restrict__ Wk,
                  const float* __restrict__ Wv, const float* __restrict__ Wo,
                  unsigned short* __restrict__ hsb,
                  unsigned short* __restrict__ wqkvb,
                  unsigned short* __restrict__ wob)
{
    const long long N0 = 8192LL * 768;          // hs
    const long long NW = 768LL * 768;           // one weight
    const long long e  = ((long long)blockIdx.x * 256 + threadIdx.x) * 8;
    const float* src; unsigned short* dst;
    if (e < N0) { src = hs + e; dst = hsb + e; }
    else if (e < N0 + 3*NW) {
        const long long r = e - N0;
        const int z = (int)(r / NW);
        src = (z == 0 ? Wq : z == 1 ? Wk : Wv) + (r - (long long)z * NW);
        dst = wqkvb + r;
    } else {
        const long long r = e - N0 - 3*NW;
        src = Wo + r; dst = wob + r;
    }
    const float4 f0 = *(const float4*)src;
    const float4 f1 = *(const float4*)(src + 4);
    u16x8 o;
    o[0]=f2bf(f0.x); o[1]=f2bf(f0.y); o[2]=f2bf(f0.z); o[3]=f2bf(f0.w);
    o[4]=f2bf(f1.x); o[5]=f2bf(f1.y); o[6]=f2bf(f1.z); o[7]=f2bf(f1.w);
    *(u16x8*)dst = o;
}

// ---------------- bf16 MFMA GEMM: C = A @ W^T (+bias) ----------------
// A: [M][768] bf16. Wt: [N][768] bf16 rows (torch weight layout).
// 128x128 tile, BK=64, 4 waves (2x2 of 64x64 quadrants), mfma 16x16x32.
// MODE 0 (QKV, N=2304): z=n0/768. z<2: fused L2-norm (+logit scale for q), bf16 out
//   to [B,H,S,64]. z==2: bf16 V^T out to [B,H,64,S].
// MODE 1: fp32 out[m][768] + bias.
template<int MODE>
__global__ __launch_bounds__(256)
void gemm_bf16(const unsigned short* __restrict__ A,
               const unsigned short* __restrict__ Wt,
               const float* __restrict__ b0, const float* __restrict__ b1,
               const float* __restrict__ b2, const float* __restrict__ ls,
               unsigned short* __restrict__ qb, unsigned short* __restrict__ kb,
               unsigned short* __restrict__ vt, float* __restrict__ out)
{
    constexpr int K = 768;
    __shared__ char As[16384];   // [128 m][64 k] bf16, chunk-swizzled
    __shared__ char Bs[16384];   // [128 n][64 k] bf16, chunk-swizzled

    const int tid = threadIdx.x, w = tid >> 6, l = tid & 63;
    const int wr = w >> 1, wc = w & 1, hi = l >> 4, ll = l & 15;
    const int n0 = blockIdx.x * 128, m0 = blockIdx.y * 128;

    // staging: wave w owns rows w*32..+31 of both tiles; 4 insts x 8 rows each.
    // lane l -> row sub (l>>3), LDS chunk (l&7); source chunk pre-swizzled.
    const int srow = l >> 3;
    const int sch  = (l & 7) ^ srow;
    const char* Ab = (const char*)(A  + (size_t)(m0 + w*32) * K) + srow * (K*2) + sch * 16;
    const char* Bb = (const char*)(Wt + (size_t)(n0 + w*32) * K) + srow * (K*2) + sch * 16;
    char* AsW = As + (w*32) * 128;
    char* BsW = Bs + (w*32) * 128;

    f32x4 acc[4][4];
    #pragma unroll
    for (int i = 0; i < 4; ++i)
        #pragma unroll
        for (int j = 0; j < 4; ++j) acc[i][j] = (f32x4){0.f,0.f,0.f,0.f};

    for (int kt = 0; kt < K/64; ++kt) {
        __syncthreads();   // prior step's frag reads done
        #pragma unroll
        for (int s = 0; s < 4; ++s) {
            gload16(Ab + kt*128 + s*8*(K*2), AsW + s*1024);
            gload16(Bb + kt*128 + s*8*(K*2), BsW + s*1024);
        }
        __syncthreads();   // staging (vmcnt) drained by barrier

        bf16x8 af[2][4], bf[2][4];
        #pragma unroll
        for (int kk = 0; kk < 2; ++kk) {
            const int pc = kk*4 + hi;
            #pragma unroll
            for (int i = 0; i < 4; ++i) {
                const int ra = wr*64 + i*16 + ll;
                af[kk][i] = *(const bf16x8*)(As + ra*128 + ((pc ^ (ra & 7)) << 4));
                const int rb = wc*64 + i*16 + ll;
                bf[kk][i] = *(const bf16x8*)(Bs + rb*128 + ((pc ^ (rb & 7)) << 4));
            }
        }
        #pragma unroll
        for (int kk = 0; kk < 2; ++kk)
            #pragma unroll
            for (int i = 0; i < 4; ++i)
                #pragma unroll
                for (int j = 0; j < 4; ++j)
                    acc[i][j] = __builtin_amdgcn_mfma_f32_16x16x32_bf16(af[kk][i], bf[kk][j], acc[i][j], 0, 0, 0);
    }

    if (MODE == 0) {
        const int z  = n0 / 768;
        const int nl = (n0 % 768) + wc*64;        // local col base within this weight
        const int h  = nl >> 6;                   // quadrant == one head
        const int b  = m0 >> 11;
        const int s0 = (m0 & (S_LEN-1)) + wr*64;
        const float* bias = (z == 0) ? b0 : (z == 1) ? b1 : b2;
        float bj[4];
        #pragma unroll
        for (int j = 0; j < 4; ++j) bj[j] = bias[nl + j*16 + ll];

        if (z < 2) {
            const float sc = (z == 0) ? expf(fminf(ls[h], MAXLS)) : 1.0f;
            unsigned short* dst = (z == 0 ? qb : kb) + ((size_t)(b*Hh + h) * S_LEN) * HD;
            #pragma unroll
            for (int i = 0; i < 4; ++i) {
                #pragma unroll
                for (int r = 0; r < 4; ++r) {
                    float v[4]; float ss = 0.f;
                    #pragma unroll
                    for (int j = 0; j < 4; ++j) { v[j] = acc[i][j][r] + bj[j]; ss += v[j]*v[j]; }
                    #pragma unroll
                    for (int mm = 1; mm < 16; mm <<= 1) ss += __shfl_xor(ss, mm, 64);
                    const float inv = sc / fmaxf(sqrtf(ss), 1e-12f);
                    const int s = s0 + i*16 + hi*4 + r;
                    #pragma unroll
                    for (int j = 0; j < 4; ++j)
                        dst[(size_t)s * HD + j*16 + ll] = f2bf(v[j] * inv);
                }
            }
        } else {
            #pragma unroll
            for (int j = 0; j < 4; ++j) {
                const int d = (nl & 63) + j*16 + ll;
                #pragma unroll
                for (int i = 0; i < 4; ++i) {
                    const int s = s0 + i*16 + hi*4;
                    u16x4 o;
                    #pragma unroll
                    for (int r = 0; r < 4; ++r) o[r] = f2bf(acc[i][j][r] + bj[j]);
                    *(u16x4*)(vt + ((size_t)(b*Hh + h) * HD + d) * S_LEN + s) = o;
                }
            }
        }
    } else {
        #pragma unroll
        for (int i = 0; i < 4; ++i)
            #pragma unroll
            for (int j = 0; j < 4; ++j) {
                const int n = n0 + wc*64 + j*16 + ll;
                const float bn = b0[n];
                #pragma unroll
                for (int r = 0; r < 4; ++r) {
                    const int m = m0 + wr*64 + i*16 + hi*4 + r;
                    out[(size_t)m * D_MODEL + n] = acc[i][j][r] + bn;
                }
            }
    }
}

// ---------------- stage a 64x64 bf16 tile into LDS with XOR chunk swizzle ----------------
__device__ __forceinline__ void stage_tile(const char* __restrict__ g, int grs,
                                           char* __restrict__ lds, int tid)
{
    #pragma unroll
    for (int i = 0; i < 2; ++i) {
        const int c = tid * 2 + i;            // 0..511
        const int row = c >> 3, kc = c & 7;
        const uint4 v = *(const uint4*)(g + (size_t)row * grs + kc * 16);
        *(uint4*)(lds + row * 128 + ((kc ^ (row & 7)) << 4)) = v;
    }
}

// ---------------- Flash attention, bf16 MFMA, 64x64 tiles, 4 waves ----------------
// q,k: bf16 [B*H][S][64] (128B rows). vT: bf16 [B*H][64][S]. ctx out: bf16 [B][S][768].
__global__ __launch_bounds__(256)
void attn_mfma(const char* __restrict__ qb_, const char* __restrict__ kb_,
               const char* __restrict__ vtb_, unsigned short* __restrict__ ctx)
{
    __shared__ char smem[32768];
    char* Qs = smem;            // [64 q][64 k] bf16 swz
    char* Ks = smem + 8192;     // [64 kv][64 k]
    char* Vs = smem + 16384;    // [64 d][64 kv]
    char* Ps = smem + 24576;    // [64 q][64 kv]

    const int flat = blockIdx.x;              // 0..1535
    const int xcd  = flat & 7;
    const int ix   = flat >> 3;
    const int bh   = xcd * 6 + (ix >> 5);
    const int q0   = (ix & 31) * 64;

    const int tid = threadIdx.x;
    const int l   = tid & 63;
    const int w   = tid >> 6;
    const int lg  = l >> 4;
    const int ll  = l & 15;

    const char* qg = qb_ + ((size_t)bh * S_LEN + q0) * 128;
    const char* kg = kb_ + (size_t)bh * S_LEN * 128;
    const char* vg = vtb_ + (size_t)bh * HD * (S_LEN * 2);

    stage_tile(qg, 128, Qs, tid);

    const int m = w * 16 + ll;
    f32x4 acco[4];
    float mrun[4], lrun[4];
    #pragma unroll
    for (int i = 0; i < 4; ++i) {
        mrun[i] = -INFINITY; lrun[i] = 0.0f;
        acco[i] = (f32x4){0.f, 0.f, 0.f, 0.f};
    }
    __syncthreads();

    bf16x8 aq[2];
    #pragma unroll
    for (int kk = 0; kk < 2; ++kk) {
        const int k8 = kk * 4 + lg;
        aq[kk] = *(const bf16x8*)(Qs + m * 128 + ((k8 ^ (m & 7)) << 4));
    }

    for (int kt = 0; kt < S_LEN / 64; ++kt) {
        __syncthreads();
        stage_tile(kg + (size_t)kt * 64 * 128, 128, Ks, tid);
        stage_tile(vg + kt * 128, S_LEN * 2, Vs, tid);
        __syncthreads();

        f32x4 accs[4];
        #pragma unroll
        for (int t = 0; t < 4; ++t) accs[t] = (f32x4){0.f, 0.f, 0.f, 0.f};
        #pragma unroll
        for (int kk = 0; kk < 2; ++kk) {
            const int k8 = kk * 4 + lg;
            #pragma unroll
            for (int t = 0; t < 4; ++t) {
                const int n = t * 16 + ll;
                const bf16x8 bk = *(const bf16x8*)(Ks + n * 128 + ((k8 ^ (n & 7)) << 4));
                accs[t] = __builtin_amdgcn_mfma_f32_16x16x32_bf16(aq[kk], bk, accs[t], 0, 0, 0);
            }
        }

        float p[4][4]; float fct[4];
        #pragma unroll
        for (int i = 0; i < 4; ++i) {
            float rm = fmaxf(fmaxf(accs[0][i], accs[1][i]), fmaxf(accs[2][i], accs[3][i]));
            #pragma unroll
            for (int mm = 1; mm < 16; mm <<= 1) rm = fmaxf(rm, __shfl_xor(rm, mm, 64));
            const float mn = fmaxf(mrun[i], rm);
            fct[i] = __expf(mrun[i] - mn);
            mrun[i] = mn;
            float rs = 0.0f;
            #pragma unroll
            for (int t = 0; t < 4; ++t) { p[t][i] = __expf(accs[t][i] - mn); rs += p[t][i]; }
            #pragma unroll
            for (int mm = 1; mm < 16; mm <<= 1) rs += __shfl_xor(rs, mm, 64);
            lrun[i] = lrun[i] * fct[i] + rs;
        }
        #pragma unroll
        for (int t = 0; t < 4; ++t)
            #pragma unroll
            for (int i = 0; i < 4; ++i) acco[t][i] *= fct[i];

        #pragma unroll
        for (int t = 0; t < 4; ++t) {
            #pragma unroll
            for (int i = 0; i < 4; ++i) {
                const int mi  = w * 16 + lg * 4 + i;
                const int col = t * 16 + ll;
                const int off = mi * 128 + (((col >> 3) ^ (mi & 7)) << 4) + (col & 7) * 2;
                *(unsigned short*)(Ps + off) = f2bf(p[t][i]);
            }
        }
        __syncthreads();

        #pragma unroll
        for (int kk = 0; kk < 2; ++kk) {
            const int k8 = kk * 4 + lg;
            const bf16x8 pa = *(const bf16x8*)(Ps + m * 128 + ((k8 ^ (m & 7)) << 4));
            #pragma unroll
            for (int t = 0; t < 4; ++t) {
                const int dn = t * 16 + ll;
                const bf16x8 bv = *(const bf16x8*)(Vs + dn * 128 + ((k8 ^ (dn & 7)) << 4));
                acco[t] = __builtin_amdgcn_mfma_f32_16x16x32_bf16(pa, bv, acco[t], 0, 0, 0);
            }
        }
    }

    const int b = bh / Hh, h = bh % Hh;
    #pragma unroll
    for (int i = 0; i < 4; ++i) {
        const float inv = 1.0f / lrun[i];
        const int s = q0 + w * 16 + lg * 4 + i;
        unsigned short* crow = ctx + ((size_t)b * S_LEN + s) * D_MODEL + h * HD;
        #pragma unroll
        for (int t = 0; t < 4; ++t) crow[t * 16 + ll] = f2bf(acco[t][i] * inv);
    }
}

extern "C" void kernel_launch(void* const* d_in, const int* in_sizes, int n_in,
                              void* d_out, int out_size, void* d_ws, size_t ws_size,
                              hipStream_t stream)
{
    const float* hs = (const float*)d_in[0];
    const float* Wq = (const float*)d_in[1];
    const float* bq = (const float*)d_in[2];
    const float* Wk = (const float*)d_in[3];
    const float* bk = (const float*)d_in[4];
    const float* Wv = (const float*)d_in[5];
    const float* bv = (const float*)d_in[6];
    const float* Wo = (const float*)d_in[7];
    const float* bo = (const float*)d_in[8];
    const float* ls = (const float*)d_in[9];
    float* out = (float*)d_out;

    const int B = 4;
    const size_t nHS = 8192ULL * 768;     // 6291456
    const size_t nW  = 768ULL * 768;      // 589824
    const size_t nPB = (size_t)B * Hh * S_LEN * HD;  // 6291456

    unsigned short* hsb   = (unsigned short*)d_ws;
    unsigned short* wqkvb = hsb + nHS;
    unsigned short* wob   = wqkvb + 3 * nW;
    unsigned short* qbuf  = wob + nW;
    unsigned short* kbuf  = qbuf + nPB;
    unsigned short* vtb   = kbuf + nPB;
    unsigned short* cbuf  = vtb + nPB;    // total ~67.6 MB

    // 1) fp32 -> bf16 conversions (hs + weights)
    hipLaunchKernelGGL(convert_bf16, dim3(4224), dim3(256), 0, stream,
                       hs, Wq, Wk, Wv, Wo, hsb, wqkvb, wob);

    // 2) fused QKV projection: MFMA + fused L2norm/scale (q,k) + V^T emit
    hipLaunchKernelGGL((gemm_bf16<0>), dim3(2304/128, 8192/128), dim3(256), 0, stream,
                       hsb, wqkvb, bq, bk, bv, ls, qbuf, kbuf, vtb, nullptr);

    // 3) flash attention (bf16 MFMA) -> ctx bf16 [B,S,D]
    hipLaunchKernelGGL(attn_mfma, dim3(32 * B * Hh), dim3(256), 0, stream,
                       (const char*)qbuf, (const char*)kbuf, (const char*)vtb, cbuf);

    // 4) output projection: bf16 MFMA -> fp32 out + bias
    hipLaunchKernelGGL((gemm_bf16<1>), dim3(768/128, 8192/128), dim3(256), 0, stream,
                       cbuf, wob, bo, nullptr, nullptr, nullptr,
                       nullptr, nullptr, nullptr, out);
}

// Round 4
// 241.059 us; speedup vs baseline: 5.9100x; 1.3803x over previous
//
#include <hip/hip_runtime.h>
#include <math.h>

#define Hh 12
#define S_LEN 2048
#define D_MODEL 768
#define HD 64

static constexpr float MAXLS = 4.6051701859880914f; // log(1/0.01)

typedef short bf16x8 __attribute__((ext_vector_type(8)));
typedef float f32x4  __attribute__((ext_vector_type(4)));
typedef float f32x16 __attribute__((ext_vector_type(16)));
typedef unsigned short u16x4 __attribute__((ext_vector_type(4)));
typedef unsigned short u16x8 __attribute__((ext_vector_type(8)));
typedef unsigned int u32x4 __attribute__((ext_vector_type(4)));

__device__ __forceinline__ unsigned short f2bf(float x) {
    unsigned int u = __builtin_bit_cast(unsigned int, x);
    unsigned int r = (u + 0x7FFF + ((u >> 16) & 1)) >> 16;
    return (unsigned short)r;
}

__device__ __forceinline__ unsigned int cvtpk(float a, float b) {
    unsigned int r;
    asm("v_cvt_pk_bf16_f32 %0, %1, %2" : "=v"(r) : "v"(a), "v"(b));
    return r;
}

__device__ __forceinline__ void gload16(const void* g, void* l) {
    __builtin_amdgcn_global_load_lds(
        (const __attribute__((address_space(1))) unsigned int*)g,
        (__attribute__((address_space(3))) unsigned int*)l, 16, 0, 0);
}

// ---------------- fp32 -> bf16 convert: hs, Wq|Wk|Wv (concat), Wo ----------------
__global__ __launch_bounds__(256)
void convert_bf16(const float* __restrict__ hs,
                  const float* __restrict__ Wq, const float* __restrict__ Wk,
                  const float* __restrict__ Wv, const float* __restrict__ Wo,
                  unsigned short* __restrict__ hsb,
                  unsigned short* __restrict__ wqkvb,
                  unsigned short* __restrict__ wob)
{
    const long long N0 = 8192LL * 768;
    const long long NW = 768LL * 768;
    const long long e  = ((long long)blockIdx.x * 256 + threadIdx.x) * 8;
    const float* src; unsigned short* dst;
    if (e < N0) { src = hs + e; dst = hsb + e; }
    else if (e < N0 + 3*NW) {
        const long long r = e - N0;
        const int z = (int)(r / NW);
        src = (z == 0 ? Wq : z == 1 ? Wk : Wv) + (r - (long long)z * NW);
        dst = wqkvb + r;
    } else {
        const long long r = e - N0 - 3*NW;
        src = Wo + r; dst = wob + r;
    }
    const float4 f0 = *(const float4*)src;
    const float4 f1 = *(const float4*)(src + 4);
    u16x8 o;
    o[0]=f2bf(f0.x); o[1]=f2bf(f0.y); o[2]=f2bf(f0.z); o[3]=f2bf(f0.w);
    o[4]=f2bf(f1.x); o[5]=f2bf(f1.y); o[6]=f2bf(f1.z); o[7]=f2bf(f1.w);
    *(u16x8*)dst = o;
}

// ---------------- bf16 MFMA GEMM: C = A @ W^T (+bias) ----------------
// MODE 0 (QKV, N=2304): z<2: fused L2-norm (+scale for q) -> bf16 [B,H,S,64].
//   z==2: bf16 V^T -> [B,H,64,S], with kv bit2<->bit3 permutation inside each
//   64-block of s (so attention's PV A-frag k-slot order matches P-word order).
// MODE 1: fp32 out[m][768] + bias.
template<int MODE>
__global__ __launch_bounds__(256)
void gemm_bf16(const unsigned short* __restrict__ A,
               const unsigned short* __restrict__ Wt,
               const float* __restrict__ b0, const float* __restrict__ b1,
               const float* __restrict__ b2, const float* __restrict__ ls,
               unsigned short* __restrict__ qb, unsigned short* __restrict__ kb,
               unsigned short* __restrict__ vt, float* __restrict__ out)
{
    constexpr int K = 768;
    __shared__ char As[16384];
    __shared__ char Bs[16384];

    const int tid = threadIdx.x, w = tid >> 6, l = tid & 63;
    const int wr = w >> 1, wc = w & 1, hi = l >> 4, ll = l & 15;
    const int n0 = blockIdx.x * 128, m0 = blockIdx.y * 128;

    const int srow = l >> 3;
    const int sch  = (l & 7) ^ srow;
    const char* Ab = (const char*)(A  + (size_t)(m0 + w*32) * K) + srow * (K*2) + sch * 16;
    const char* Bb = (const char*)(Wt + (size_t)(n0 + w*32) * K) + srow * (K*2) + sch * 16;
    char* AsW = As + (w*32) * 128;
    char* BsW = Bs + (w*32) * 128;

    f32x4 acc[4][4];
    #pragma unroll
    for (int i = 0; i < 4; ++i)
        #pragma unroll
        for (int j = 0; j < 4; ++j) acc[i][j] = (f32x4){0.f,0.f,0.f,0.f};

    for (int kt = 0; kt < K/64; ++kt) {
        __syncthreads();
        #pragma unroll
        for (int s = 0; s < 4; ++s) {
            gload16(Ab + kt*128 + s*8*(K*2), AsW + s*1024);
            gload16(Bb + kt*128 + s*8*(K*2), BsW + s*1024);
        }
        __syncthreads();

        bf16x8 af[2][4], bf[2][4];
        #pragma unroll
        for (int kk = 0; kk < 2; ++kk) {
            const int pc = kk*4 + hi;
            #pragma unroll
            for (int i = 0; i < 4; ++i) {
                const int ra = wr*64 + i*16 + ll;
                af[kk][i] = *(const bf16x8*)(As + ra*128 + ((pc ^ (ra & 7)) << 4));
                const int rb = wc*64 + i*16 + ll;
                bf[kk][i] = *(const bf16x8*)(Bs + rb*128 + ((pc ^ (rb & 7)) << 4));
            }
        }
        #pragma unroll
        for (int kk = 0; kk < 2; ++kk)
            #pragma unroll
            for (int i = 0; i < 4; ++i)
                #pragma unroll
                for (int j = 0; j < 4; ++j)
                    acc[i][j] = __builtin_amdgcn_mfma_f32_16x16x32_bf16(af[kk][i], bf[kk][j], acc[i][j], 0, 0, 0);
    }

    if (MODE == 0) {
        const int z  = n0 / 768;
        const int nl = (n0 % 768) + wc*64;
        const int h  = nl >> 6;
        const int b  = m0 >> 11;
        const int s0 = (m0 & (S_LEN-1)) + wr*64;
        const float* bias = (z == 0) ? b0 : (z == 1) ? b1 : b2;
        float bj[4];
        #pragma unroll
        for (int j = 0; j < 4; ++j) bj[j] = bias[nl + j*16 + ll];

        if (z < 2) {
            const float sc = (z == 0) ? expf(fminf(ls[h], MAXLS)) : 1.0f;
            unsigned short* dst = (z == 0 ? qb : kb) + ((size_t)(b*Hh + h) * S_LEN) * HD;
            #pragma unroll
            for (int i = 0; i < 4; ++i) {
                #pragma unroll
                for (int r = 0; r < 4; ++r) {
                    float v[4]; float ss = 0.f;
                    #pragma unroll
                    for (int j = 0; j < 4; ++j) { v[j] = acc[i][j][r] + bj[j]; ss += v[j]*v[j]; }
                    #pragma unroll
                    for (int mm = 1; mm < 16; mm <<= 1) ss += __shfl_xor(ss, mm, 64);
                    const float inv = sc / fmaxf(sqrtf(ss), 1e-12f);
                    const int s = s0 + i*16 + hi*4 + r;
                    #pragma unroll
                    for (int j = 0; j < 4; ++j)
                        dst[(size_t)s * HD + j*16 + ll] = f2bf(v[j] * inv);
                }
            }
        } else {
            // V^T with kv-permutation: swap bits 2,3 of s within each 64-block
            const int hsw = ((hi & 1) << 1) | (hi >> 1);
            #pragma unroll
            for (int j = 0; j < 4; ++j) {
                const int d = (nl & 63) + j*16 + ll;
                #pragma unroll
                for (int i = 0; i < 4; ++i) {
                    const int s = s0 + i*16 + hsw*4;
                    u16x4 o;
                    #pragma unroll
                    for (int r = 0; r < 4; ++r) o[r] = f2bf(acc[i][j][r] + bj[j]);
                    *(u16x4*)(vt + ((size_t)(b*Hh + h) * HD + d) * S_LEN + s) = o;
                }
            }
        }
    } else {
        #pragma unroll
        for (int i = 0; i < 4; ++i)
            #pragma unroll
            for (int j = 0; j < 4; ++j) {
                const int n = n0 + wc*64 + j*16 + ll;
                const float bn = b0[n];
                #pragma unroll
                for (int r = 0; r < 4; ++r) {
                    const int m = m0 + wr*64 + i*16 + hi*4 + r;
                    out[(size_t)m * D_MODEL + n] = acc[i][j][r] + bn;
                }
            }
    }
}

// ---------------- Flash attention v2: 32x32x16 MFMA, S^T orientation ----------------
// Block: 4 waves x 32 q = 128 q rows. LDS: K tile 8KB + V tile 8KB.
// No online max (scores bounded by sc). P stays in registers (V kv-permuted).
__global__ __launch_bounds__(256)
void attn_mfma2(const char* __restrict__ qb_, const char* __restrict__ kb_,
                const char* __restrict__ vtb_, const float* __restrict__ ls,
                unsigned short* __restrict__ ctx)
{
    __shared__ char smem[16384];
    char* Ks = smem;            // [64 kv][128B] swz
    char* Vs = smem + 8192;     // [64 d][128B] swz (kv pre-permuted in vT)

    const int flat = blockIdx.x;          // 0..767
    const int xcd = flat & 7, ix = flat >> 3;
    const int bh = xcd * 6 + (ix >> 4);   // 6 bh per XCD
    const int q0 = (ix & 15) * 128;
    const int b = bh / Hh, h = bh % Hh;

    const int tid = threadIdx.x, w = tid >> 6, l = tid & 63;
    const int lq = l & 31, g = l >> 5;

    const float c1 = 1.4426950408889634f;
    const float sc = __expf(fminf(ls[h], MAXLS));
    const float c0 = -sc * c1;

    const char* qg = qb_ + ((size_t)bh * S_LEN + q0 + w * 32) * 128;
    const char* kg = kb_ + (size_t)bh * S_LEN * 128;
    const char* vg = vtb_ + (size_t)bh * HD * (S_LEN * 2);

    // Q B-frags: lane = col q (lq), k-elems d = s*16 + g*8 + j
    bf16x8 qf[4];
    #pragma unroll
    for (int s = 0; s < 4; ++s)
        qf[s] = *(const bf16x8*)(qg + lq * 128 + s * 32 + g * 16);

    f32x16 acco0, acco1;
    #pragma unroll
    for (int i = 0; i < 16; ++i) { acco0[i] = 0.f; acco1[i] = 0.f; }
    float lsum = 0.f;

    const int srow = l >> 3;
    const int schb = ((l & 7) ^ srow) << 4;
    const char* kst = kg + (size_t)(w * 16 + srow) * 128 + schb;
    const char* vst = vg + (size_t)(w * 16 + srow) * 4096 + schb;
    char* kld = Ks + (w * 16) * 128;
    char* vld = Vs + (w * 16) * 128;
    const int swzq = (lq & 7);

    for (int kt = 0; kt < S_LEN / 64; ++kt) {
        __syncthreads();
        gload16(kst + kt * 8192, kld);
        gload16(kst + kt * 8192 + 8 * 128, kld + 1024);
        gload16(vst + kt * 128, vld);
        gload16(vst + kt * 128 + (size_t)8 * 4096, vld + 1024);
        __syncthreads();

        // S^T = K . Q^T : rows kv, cols q (lane owns col q = lq)
        f32x16 sa0, sa1;
        #pragma unroll
        for (int i = 0; i < 16; ++i) { sa0[i] = 0.f; sa1[i] = 0.f; }

        __builtin_amdgcn_s_setprio(1);
        #pragma unroll
        for (int s = 0; s < 4; ++s) {
            const int c = 2 * s + g;
            const bf16x8 kf0 = *(const bf16x8*)(Ks + lq * 128 + ((c ^ swzq) << 4));
            sa0 = __builtin_amdgcn_mfma_f32_32x32x16_bf16(kf0, qf[s], sa0, 0, 0, 0);
            const bf16x8 kf1 = *(const bf16x8*)(Ks + (32 + lq) * 128 + ((c ^ swzq) << 4));
            sa1 = __builtin_amdgcn_mfma_f32_32x32x16_bf16(kf1, qf[s], sa1, 0, 0, 0);
        }
        __builtin_amdgcn_s_setprio(0);

        // softmax (no max needed: s <= sc) + pack to bf16 pairs
        unsigned int pw[2][8];
        #pragma unroll
        for (int n = 0; n < 2; ++n) {
            const f32x16 sv = n ? sa1 : sa0;
            #pragma unroll
            for (int m = 0; m < 4; ++m) {
                const float p0 = __builtin_amdgcn_exp2f(fmaf(sv[4*m+0], c1, c0));
                const float p1 = __builtin_amdgcn_exp2f(fmaf(sv[4*m+1], c1, c0));
                const float p2 = __builtin_amdgcn_exp2f(fmaf(sv[4*m+2], c1, c0));
                const float p3 = __builtin_amdgcn_exp2f(fmaf(sv[4*m+3], c1, c0));
                lsum += (p0 + p1) + (p2 + p3);
                pw[n][2*m]   = cvtpk(p0, p1);
                pw[n][2*m+1] = cvtpk(p2, p3);
            }
        }

        // O^acc += P.V : A-frag = own p-words (kv order matches via V-permutation)
        __builtin_amdgcn_s_setprio(1);
        #pragma unroll
        for (int t = 0; t < 4; ++t) {
            u32x4 pu;
            pu[0] = pw[t>>1][4*(t&1)+0];
            pu[1] = pw[t>>1][4*(t&1)+1];
            pu[2] = pw[t>>1][4*(t&1)+2];
            pu[3] = pw[t>>1][4*(t&1)+3];
            const bf16x8 pa = __builtin_bit_cast(bf16x8, pu);
            const int c = 2 * t + g;
            const bf16x8 vf0 = *(const bf16x8*)(Vs + lq * 128 + ((c ^ swzq) << 4));
            acco0 = __builtin_amdgcn_mfma_f32_32x32x16_bf16(pa, vf0, acco0, 0, 0, 0);
            const bf16x8 vf1 = *(const bf16x8*)(Vs + (32 + lq) * 128 + ((c ^ swzq) << 4));
            acco1 = __builtin_amdgcn_mfma_f32_32x32x16_bf16(pa, vf1, acco1, 0, 0, 0);
        }
        __builtin_amdgcn_s_setprio(0);
    }

    // epilogue: O[q][d] = acc / lsum ; ctx bf16 [B][S][768]
    lsum += __shfl_xor(lsum, 32, 64);
    #pragma unroll
    for (int r = 0; r < 16; ++r) {
        const int qrow = (r & 3) + 8 * (r >> 2) + 4 * g;
        const float inv = 1.0f / __shfl(lsum, (l & 32) | qrow, 64);
        unsigned short* crow = ctx + ((size_t)b * S_LEN + q0 + w * 32 + qrow) * D_MODEL + h * HD;
        crow[lq]      = f2bf(acco0[r] * inv);
        crow[32 + lq] = f2bf(acco1[r] * inv);
    }
}

extern "C" void kernel_launch(void* const* d_in, const int* in_sizes, int n_in,
                              void* d_out, int out_size, void* d_ws, size_t ws_size,
                              hipStream_t stream)
{
    const float* hs = (const float*)d_in[0];
    const float* Wq = (const float*)d_in[1];
    const float* bq = (const float*)d_in[2];
    const float* Wk = (const float*)d_in[3];
    const float* bk = (const float*)d_in[4];
    const float* Wv = (const float*)d_in[5];
    const float* bv = (const float*)d_in[6];
    const float* Wo = (const float*)d_in[7];
    const float* bo = (const float*)d_in[8];
    const float* ls = (const float*)d_in[9];
    float* out = (float*)d_out;

    const int B = 4;
    const size_t nHS = 8192ULL * 768;
    const size_t nW  = 768ULL * 768;
    const size_t nPB = (size_t)B * Hh * S_LEN * HD;

    unsigned short* hsb   = (unsigned short*)d_ws;
    unsigned short* wqkvb = hsb + nHS;
    unsigned short* wob   = wqkvb + 3 * nW;
    unsigned short* qbuf  = wob + nW;
    unsigned short* kbuf  = qbuf + nPB;
    unsigned short* vtb   = kbuf + nPB;
    unsigned short* cbuf  = vtb + nPB;

    hipLaunchKernelGGL(convert_bf16, dim3(4224), dim3(256), 0, stream,
                       hs, Wq, Wk, Wv, Wo, hsb, wqkvb, wob);

    hipLaunchKernelGGL((gemm_bf16<0>), dim3(2304/128, 8192/128), dim3(256), 0, stream,
                       hsb, wqkvb, bq, bk, bv, ls, qbuf, kbuf, vtb, nullptr);

    hipLaunchKernelGGL(attn_mfma2, dim3((S_LEN/128) * B * Hh), dim3(256), 0, stream,
                       (const char*)qbuf, (const char*)kbuf, (const char*)vtb, ls, cbuf);

    hipLaunchKernelGGL((gemm_bf16<1>), dim3(768/128, 8192/128), dim3(256), 0, stream,
                       cbuf, wob, bo, nullptr, nullptr, nullptr,
                       nullptr, nullptr, nullptr, out);
}